// Round 19
// baseline (83.142 us; speedup 1.0000x reference)
//
#include <hip/hip_runtime.h>
#include <math.h>

typedef unsigned long long u64;
typedef __attribute__((ext_vector_type(8))) short bf16x8;
typedef __attribute__((ext_vector_type(4))) float f32x4;

#define S_DIM 1023
#define B_DIM 64
#define I_DIM 1024
#define CTX_DIM 784
#define CTX4 196          // CTX_DIM / 4
#define NWROWS 16         // 2^M buckets
#define NTASK (S_DIM * NWROWS)

#define LR_C 0.01f
#define WC_C 5.0f
#define LO_C (-6.906754778648554f)
#define HI_C ( 6.906754778648554f)

__device__ __forceinline__ float dot4(float4 a, float4 b) {
    return a.x * b.x + a.y * b.y + a.z * b.z + a.w * b.w;
}

__device__ __forceinline__ float4 upd4(float4 w, float4 a, float c) {
    float4 r;
    r.x = fminf(fmaxf(w.x - c * a.x, -WC_C), WC_C);
    r.y = fminf(fmaxf(w.y - c * a.y, -WC_C), WC_C);
    r.z = fminf(fmaxf(w.z - c * a.z, -WC_C), WC_C);
    r.w = fminf(fmaxf(w.w - c * a.w, -WC_C), WC_C);
    return r;
}

__device__ __forceinline__ short f2bf(float f) {
    union { float f; unsigned u; } cv; cv.f = f;
    unsigned r = cv.u + 0x7fffu + ((cv.u >> 16) & 1u);   // RNE
    return (short)(r >> 16);
}

// ---------------- kernel 1: prep -- ctxT4 transpose + bias row ----------------
__global__ __launch_bounds__(256) void prep_kernel(
    const float* __restrict__ context,   // [B, CTX]
    const float* __restrict__ bias,      // [1]
    float4* __restrict__ ctxT4,          // [CTX4][B]
    float* __restrict__ out_logits)      // [B, S+1]
{
    int g = blockIdx.x * 256 + threadIdx.x;
    int k4 = g >> 6;
    int b  = g & 63;
    ctxT4[g] = *(const float4*)(context + (size_t)b * CTX_DIM + k4 * 4);
    if (g < B_DIM) out_logits[(size_t)g * (S_DIM + 1)] = bias[0];
}

// ---------------- kernel 2: mega -- pack_logit (32 blocks) + idx (1023 blocks) ----------------
// Small LDS footprint -> high occupancy; idx runs at its proven standalone speed.
__global__ __launch_bounds__(256) void mega_kernel(
    const float* __restrict__ logit,     // [B, I]
    const float* __restrict__ cm,        // [S, 4, CTX]
    const float* __restrict__ cb,        // [S, 4]
    const float4* __restrict__ ctxT4,    // [CTX4][B]
    short* __restrict__ pack_b,          // [4*32*64*8]
    u64* __restrict__ mask_g,            // [S*16]
    int* __restrict__ lastb_g)           // [S*16]
{
    __shared__ float red[4][4][64];
    __shared__ int   bits[4][64];
    __shared__ float cb_lds[4];

    const int blk = blockIdx.x;
    const int t = threadIdx.x;

    if (blk < 32) {   // ---- pack_logit family ----
        int g = blk * 256 + t;               // (nt*32+kb)*64 + l
        int l  = g & 63;
        int kb = (g >> 6) & 31;
        int nt = g >> 11;
        int b  = nt * 16 + (l & 15);
        int i0 = kb * 32 + (l >> 4) * 8;
        const float* src = logit + (size_t)b * I_DIM + i0;
        bf16x8 v;
        #pragma unroll
        for (int j = 0; j < 8; ++j) v[j] = f2bf(src[j]);
        *(bf16x8*)(pack_b + (size_t)g * 8) = v;
        return;
    }

    // ---- idx family ----
    const int s = blk - 32;
    if (t < 4) cb_lds[t] = cb[s * 4 + t];

    const int b = t & 63;
    const int q = __builtin_amdgcn_readfirstlane(t >> 6);
    const float4* cmr = (const float4*)(cm + (size_t)s * 4 * CTX_DIM);

    float a0 = 0.f, a1 = 0.f, a2 = 0.f, a3 = 0.f;
    const int k0 = q * 49;
    #pragma unroll 7
    for (int kk = 0; kk < 49; ++kk) {
        int k4 = k0 + kk;
        float4 c4 = ctxT4[k4 * 64 + b];
        a0 += dot4(cmr[k4], c4);
        a1 += dot4(cmr[CTX4 + k4], c4);
        a2 += dot4(cmr[2 * CTX4 + k4], c4);
        a3 += dot4(cmr[3 * CTX4 + k4], c4);
    }
    red[q][0][b] = a0;
    red[q][1][b] = a1;
    red[q][2][b] = a2;
    red[q][3][b] = a3;
    __syncthreads();

    {
        int m = t >> 6, bb = t & 63;
        float sum = red[0][m][bb] + red[1][m][bb] + red[2][m][bb] + red[3][m][bb];
        bits[m][bb] = (sum > cb_lds[m]) ? 1 : 0;
    }
    __syncthreads();

    if (t < B_DIM) {
        int v = bits[0][t] + 2 * bits[1][t] + 4 * bits[2][t] + 8 * bits[3][t];
        u64 my = 0;
        #pragma unroll
        for (int kk = 0; kk < NWROWS; ++kk) {
            u64 mk = __ballot(v == kk);
            if (t == kk) my = mk;
        }
        if (t < NWROWS) {
            mask_g[s * NWROWS + t]  = my;
            lastb_g[s * NWROWS + t] = my ? (63 - __clzll(my)) : -1;
        }
    }
}

// ---------------- kernel 3: dots -- NO LDS, NO barriers, read-only stream ----------------
// A-fragments straight from fp32 W (lanes l,l+16,l+32,l+48 cover one 128B row
// segment -> full line utilization), cvt in-loop, B from L2-hot pack_b.
// Selection reads mask/lastb from L2 directly; coef written to global.
__global__ __launch_bounds__(256, 4) void gln_dots_kernel(
    const float* __restrict__ logit,     // [B, I] (unused, kept for symmetry)
    const float* __restrict__ target,    // [B]
    const float* __restrict__ weights,   // [S, 16, I] fp32
    const u64*   __restrict__ mask_g,    // [S*16]
    const int*   __restrict__ lastb_g,   // [S*16]
    const short* __restrict__ pack_b,    // bf16 B-fragments
    float* __restrict__ out_logits,      // [B, S+1]
    float* __restrict__ coef_g)          // [S*16]
{
    const int s  = blockIdx.x;
    const int t  = threadIdx.x;
    const int wv = t >> 6;
    const int l  = t & 63;

    // A-frag base: lane l holds A[row=l&15][k=(l>>4)*8+j]  (R10-verified layout)
    const float* Abase = weights + (size_t)s * (NWROWS * I_DIM)
                       + (size_t)(l & 15) * I_DIM + ((l >> 4) * 8);
    const bf16x8* Bb = (const bf16x8*)pack_b + (size_t)wv * 2048 + l;

    f32x4 acc = {0.f, 0.f, 0.f, 0.f};
    #pragma unroll 4
    for (int kb = 0; kb < 32; ++kb) {
        float4 x = *(const float4*)(Abase + kb * 32);
        float4 y = *(const float4*)(Abase + kb * 32 + 4);
        bf16x8 af;
        af[0] = f2bf(x.x); af[1] = f2bf(x.y); af[2] = f2bf(x.z); af[3] = f2bf(x.w);
        af[4] = f2bf(y.x); af[5] = f2bf(y.y); af[6] = f2bf(y.z); af[7] = f2bf(y.w);
        bf16x8 bfr = Bb[(size_t)kb * 64];
        acc = __builtin_amdgcn_mfma_f32_16x16x32_bf16(af, bfr, acc, 0, 0, 0);
    }

    // selection: C-layout col=l&15 (within wave tile), row=(l>>4)*4+j
    const int col = wv * 16 + (l & 15);
    const int q2  = l >> 4;
    #pragma unroll
    for (int j = 0; j < 4; ++j) {
        int r = q2 * 4 + j;
        u64 m = mask_g[s * NWROWS + r];          // L2-hot
        if ((m >> col) & 1) {
            float o = fminf(fmaxf(acc[j], LO_C), HI_C);
            out_logits[(size_t)col * (S_DIM + 1) + s + 1] = o;
            if (col == lastb_g[s * NWROWS + r])
                coef_g[s * NWROWS + r] = LR_C * (1.0f / (1.0f + expf(-o)) - target[col]);
        }
    }
}

// ---------------- kernel 4: streaming update (proven ~11us shape) ----------------
__global__ __launch_bounds__(256) void gln_upd_kernel(
    const float* __restrict__ logit,     // [B, I]
    const float* __restrict__ weights,   // [S*16*I]
    const int*   __restrict__ lastb_g,   // [S*16]
    const float* __restrict__ coef_g,    // [S*16]
    float* __restrict__ new_weights)
{
    const int total = NTASK * 256;       // float4 count
    const int stride = gridDim.x * 256;
    for (int g = blockIdx.x * 256 + threadIdx.x; g < total; g += stride) {
        const int task = g >> 8;
        const int off  = g & 255;
        const int lb   = lastb_g[task];          // wave-uniform (256 f4 per task)
        float4 w = ((const float4*)weights)[g];
        float4 r;
        if (lb < 0) {
            r = w;
        } else {
            const float c = coef_g[task];
            float4 a = ((const float4*)logit)[lb * 256 + off];
            r = upd4(w, a, c);
        }
        ((float4*)new_weights)[g] = r;
    }
}

extern "C" void kernel_launch(void* const* d_in, const int* in_sizes, int n_in,
                              void* d_out, int out_size, void* d_ws, size_t ws_size,
                              hipStream_t stream) {
    const float* logit   = (const float*)d_in[0];   // [B, I, 1]
    const float* context = (const float*)d_in[1];   // [B, CTX]
    const float* target  = (const float*)d_in[2];   // [B, 1]
    const float* cm      = (const float*)d_in[3];   // [1, S, 4, CTX]
    const float* cb      = (const float*)d_in[4];   // [1, S, 4, 1]
    const float* weights = (const float*)d_in[5];   // [1, S, 16, I]
    const float* bias    = (const float*)d_in[6];   // [1]

    float* out_logits  = (float*)d_out;                       // [B, S+1]
    float* new_weights = out_logits + (size_t)B_DIM * (S_DIM + 1);

    char* ws = (char*)d_ws;
    float4* ctxT4   = (float4*)ws;   ws += (size_t)CTX4 * B_DIM * 16;   // 200704 B
    short*  packb   = (short*)ws;    ws += (size_t)4 * 32 * 64 * 8 * 2; // 131072 B
    u64*    mask_g  = (u64*)ws;      ws += (size_t)NTASK * 8;           // 130944 B
    int*    lastb_g = (int*)ws;      ws += (size_t)NTASK * 4;           //  65472 B
    float*  coef_g  = (float*)ws;                                       //  65472 B

    prep_kernel<<<CTX4 * B_DIM / 256, 256, 0, stream>>>(context, bias, ctxT4, out_logits);
    mega_kernel<<<32 + S_DIM, 256, 0, stream>>>(logit, cm, cb, ctxT4,
                                                packb, mask_g, lastb_g);
    gln_dots_kernel<<<S_DIM, 256, 0, stream>>>(logit, target, weights, mask_g, lastb_g,
                                               packb, out_logits, coef_g);
    gln_upd_kernel<<<8192, 256, 0, stream>>>(logit, weights, lastb_g, coef_g, new_weights);
}